// Round 6
// baseline (633.634 us; speedup 1.0000x reference)
//
#include <hip/hip_runtime.h>

#define N_USERS 100000
#define N_ITEMS 50000
#define N_TOTAL 150000
#define DIM 64
#define NNZ_C 4800000
#define NELEM (N_TOTAL * DIM)        // 9,600,000 elements
#define NELEM4 (NELEM / 4)           // 2,400,000 x4-vectors

#define RPB 74                       // rows per bucket
#define NB 2048                      // buckets (2048*74 >= 150000)
#define NBLK 800                     // scatter blocks
#define CHUNK (NNZ_C / NBLK)         // 6000 nnz per scatter block (exact)
#define TILES 32                     // column-scan tiles over the block dim
#define TB (NBLK / TILES)            // 25 blocks per tile
#define CAP 4096                     // max entries/bucket staged (mean 2344)
#define NBUCK ((N_TOTAL + RPB - 1) / RPB)   // 2028 buckets
#define NSLAB 10                     // column slabs of 16384 cols (2 MB of x)
#define NKEY (NSLAB * RPB)           // 740 sort keys per bucket

typedef unsigned short ush;

__device__ __forceinline__ float bf2f(ush u) {
    return __uint_as_float(((unsigned)u) << 16);
}
__device__ __forceinline__ ush f2bf(float f) {   // round-to-nearest-even
    unsigned u = __float_as_uint(f);
    return (ush)((u + 0x7fffu + ((u >> 16) & 1u)) >> 16);
}

// init: A(bf16) = concat(user,item) = e0
__global__ __launch_bounds__(256) void init_kernel(
    const float4* __restrict__ user, const float4* __restrict__ item,
    ushort4* __restrict__ A16) {
    int i = blockIdx.x * 256 + threadIdx.x;
    if (i >= NELEM4) return;
    const int u4 = N_USERS * DIM / 4;
    float4 v = (i < u4) ? user[i] : item[i - u4];
    ushort4 b;
    b.x = f2bf(v.x); b.y = f2bf(v.y); b.z = f2bf(v.z); b.w = f2bf(v.w);
    A16[i] = b;
}

// P1: per-block bucket histogram in LDS -> histmat[block][bucket] (ushort)
__global__ __launch_bounds__(1024) void p1_hist(
    const int* __restrict__ row, ush* __restrict__ histmat) {
    __shared__ int h[NB];
    int t = threadIdx.x, b = blockIdx.x;
    for (int j = t; j < NB; j += 1024) h[j] = 0;
    __syncthreads();
    int kbeg = b * CHUNK;
    for (int k = kbeg + t; k < kbeg + CHUNK; k += 1024) {
        unsigned r = (unsigned)row[k];
        atomicAdd(&h[r / RPB], 1);
    }
    __syncthreads();
    for (int j = t; j < NB; j += 1024) histmat[b * NB + j] = (ush)h[j];
}

// p2a1: tilesum[tile][j] = sum of TB consecutive blocks' counts
__global__ __launch_bounds__(256) void p2a1_tilesum(
    const ush* __restrict__ histmat, ush* __restrict__ tilesum) {
    int j = blockIdx.x * 256 + threadIdx.x;
    int b0 = blockIdx.y * TB;
    int s = 0;
    #pragma unroll
    for (int i = 0; i < TB; i++) s += histmat[(b0 + i) * NB + j];
    tilesum[blockIdx.y * NB + j] = (ush)s;
}

// p2ab: per-column scan over tile sums -> tilebase; exclusive scan of
// bucket totals -> bucketbase; plus the rsp sentinel.
__global__ __launch_bounds__(1024) void p2ab_scan(
    const ush* __restrict__ tilesum, ush* __restrict__ tilebase,
    int* __restrict__ bucketbase, int* __restrict__ rsp) {
    __shared__ int s[1024];
    int t = threadIdx.x;
    int j0 = 2 * t, j1 = 2 * t + 1;
    int r0 = 0, r1 = 0;
    #pragma unroll
    for (int tl = 0; tl < TILES; tl++) {
        tilebase[tl * NB + j0] = (ush)r0;
        tilebase[tl * NB + j1] = (ush)r1;
        r0 += tilesum[tl * NB + j0];
        r1 += tilesum[tl * NB + j1];
    }
    int pair = r0 + r1;
    s[t] = pair;
    __syncthreads();
    for (int off = 1; off < 1024; off <<= 1) {
        int w = (t >= off) ? s[t - off] : 0;
        __syncthreads();
        s[t] += w;
        __syncthreads();
    }
    int excl = s[t] - pair;
    bucketbase[j0] = excl;
    bucketbase[j1] = excl + r0;
    if (t == 1023) { bucketbase[NB] = s[t]; rsp[NBUCK * NKEY] = NNZ_C; }
}

// p2a3: expand within each tile -> basemat[b][j]
__global__ __launch_bounds__(256) void p2a3_expand(
    const ush* __restrict__ histmat, const ush* __restrict__ tilebase,
    ush* __restrict__ basemat) {
    int j = blockIdx.x * 256 + threadIdx.x;
    int b0 = blockIdx.y * TB;
    int run = tilebase[blockIdx.y * NB + j];
    #pragma unroll
    for (int i = 0; i < TB; i++) {
        basemat[(b0 + i) * NB + j] = (ush)run;
        run += histmat[(b0 + i) * NB + j];
    }
}

// P3: bucket-sort the chunk in LDS, write runs of consecutive global slots.
__global__ __launch_bounds__(1024) void p3_scatter(
    const int* __restrict__ row, const int* __restrict__ col,
    const float* __restrict__ vals, const ush* __restrict__ histmat,
    const ush* __restrict__ basemat, const int* __restrict__ bucketbase,
    uint2* __restrict__ entries) {
    __shared__ int s[1024];
    __shared__ int wp[NB];
    __shared__ int gbase[NB];
    __shared__ uint2 sorted[CHUNK];
    __shared__ ush jarr[CHUNK];
    int t = threadIdx.x, b = blockIdx.x;

    int c0 = histmat[b * NB + 2 * t];
    int c1 = histmat[b * NB + 2 * t + 1];
    int pair = c0 + c1;
    s[t] = pair;
    __syncthreads();
    for (int off = 1; off < 1024; off <<= 1) {
        int w = (t >= off) ? s[t - off] : 0;
        __syncthreads();
        s[t] += w;
        __syncthreads();
    }
    int excl = s[t] - pair;
    wp[2 * t] = excl;
    wp[2 * t + 1] = excl + c0;
    gbase[2 * t]     = bucketbase[2 * t]     + (int)basemat[b * NB + 2 * t]     - excl;
    gbase[2 * t + 1] = bucketbase[2 * t + 1] + (int)basemat[b * NB + 2 * t + 1] - (excl + c0);
    __syncthreads();

    int kbeg = b * CHUNK;
    for (int k = kbeg + t; k < kbeg + CHUNK; k += 1024) {
        unsigned r = (unsigned)row[k];
        unsigned j = r / RPB;
        unsigned rl = r - j * RPB;
        int pos = atomicAdd(&wp[j], 1);
        sorted[pos] = make_uint2((rl << 18) | (unsigned)col[k],
                                 __float_as_uint(vals[k]));
        jarr[pos] = (ush)j;
    }
    __syncthreads();
    for (int i = t; i < CHUNK; i += 1024)
        entries[gbase[jarr[i]] + i] = sorted[i];
}

// P4: one block per bucket; counting-sort by key = (col-slab, local row),
// rewrite region as int2{col,val}; emit rsp[bucket][slab][rl] offsets.
__global__ __launch_bounds__(512) void p4_sort(
    const int* __restrict__ bucketbase, uint2* __restrict__ entries,
    int* __restrict__ rsp) {
    __shared__ uint2 stage[CAP];       // 32 KB
    __shared__ int cnt[1024];
    __shared__ int s[512];
    __shared__ int wp[1024];
    int t = threadIdx.x, b = blockIdx.x;
    int base = bucketbase[b];
    int n = bucketbase[b + 1] - base;
    if (n > CAP) n = CAP;
    cnt[t] = 0; cnt[t + 512] = 0;
    __syncthreads();
    for (int i = t; i < n; i += 512) {
        uint2 e = entries[base + i];
        stage[i] = e;
        int key = (int)((e.x & 0x3FFFFu) >> 14) * RPB + (int)(e.x >> 18);
        atomicAdd(&cnt[key], 1);
    }
    __syncthreads();
    int c0 = cnt[2 * t], c1 = cnt[2 * t + 1];
    int pair = c0 + c1;
    s[t] = pair;
    __syncthreads();
    for (int off = 1; off < 512; off <<= 1) {
        int w = (t >= off) ? s[t - off] : 0;
        __syncthreads();
        s[t] += w;
        __syncthreads();
    }
    int excl = s[t] - pair;
    wp[2 * t] = excl;
    wp[2 * t + 1] = excl + c0;
    __syncthreads();
    for (int k = t; k < NKEY; k += 512)
        rsp[b * NKEY + k] = base + wp[k];
    __syncthreads();                    // rsp emitted before wp mutates
    for (int i = t; i < n; i += 512) {
        uint2 e = stage[i];
        int key = (int)((e.x & 0x3FFFFu) >> 14) * RPB + (int)(e.x >> 18);
        int pos = atomicAdd(&wp[key], 1);
        ((int2*)entries)[base + pos] =
            make_int2((int)(e.x & 0x3FFFFu), (int)e.y);
    }
}

// Slab SpMM: one persistent block per bucket (2028 = 8/CU co-resident),
// fp32 acc tile in LDS (plain rmw, NO atomics: each 16-lane group owns
// rows rl ≡ grp (mod 16) for the whole kernel). Slab-major sweep keeps
// the 2 MB x-slab L2-resident chip-wide (soft sync via equal work/slab).
__global__ __launch_bounds__(256, 8) void spmm_slab_kernel(
    const int* __restrict__ rsp, const int2* __restrict__ csr,
    const ushort4* __restrict__ x4, ushort4* __restrict__ y4) {
    __shared__ float acc[RPB * DIM];   // 18944 B -> 8 blocks/CU
    int t = threadIdx.x, b = blockIdx.x;
    int grp = t >> 4, ch = t & 15;
    for (int i = t; i < RPB * DIM; i += 256) acc[i] = 0.f;
    __syncthreads();
    float4* acc4 = (float4*)acc;
    for (int s = 0; s < NSLAB; s++) {
        for (int rbase = 0; rbase < RPB; rbase += 16) {
            int rl = rbase + grp;
            if (rl >= RPB) continue;
            int idx = b * NKEY + s * RPB + rl;
            int st = rsp[idx], en = rsp[idx + 1];
            if (en <= st) continue;
            float4 f = make_float4(0.f, 0.f, 0.f, 0.f);
            int k = st;
            for (; k + 2 <= en; k += 2) {       // 2-way unroll for MLP
                int2 e0 = csr[k], e1 = csr[k + 1];
                ushort4 xa = x4[e0.x * 16 + ch];
                ushort4 xb = x4[e1.x * 16 + ch];
                float va = __int_as_float(e0.y), vb = __int_as_float(e1.y);
                f.x += va * bf2f(xa.x) + vb * bf2f(xb.x);
                f.y += va * bf2f(xa.y) + vb * bf2f(xb.y);
                f.z += va * bf2f(xa.z) + vb * bf2f(xb.z);
                f.w += va * bf2f(xa.w) + vb * bf2f(xb.w);
            }
            if (k < en) {
                int2 e0 = csr[k];
                ushort4 xa = x4[e0.x * 16 + ch];
                float va = __int_as_float(e0.y);
                f.x += va * bf2f(xa.x); f.y += va * bf2f(xa.y);
                f.z += va * bf2f(xa.z); f.w += va * bf2f(xa.w);
            }
            float4 a = acc4[rl * 16 + ch];
            a.x += f.x; a.y += f.y; a.z += f.z; a.w += f.w;
            acc4[rl * 16 + ch] = a;
        }
    }
    __syncthreads();
    int rbeg = b * RPB;
    int nr = min(RPB, N_TOTAL - rbeg);
    for (int i = t; i < nr * 16; i += 256) {
        int rl = i >> 4, c = i & 15;
        float4 a = acc4[rl * 16 + c];
        ushort4 o;
        o.x = f2bf(a.x); o.y = f2bf(a.y); o.z = f2bf(a.z); o.w = f2bf(a.w);
        y4[(rbeg + rl) * 16 + c] = o;
    }
}

// final layer fused with merge: out = (e0 + e1 + e2 + S*e2) * 0.25
__global__ __launch_bounds__(256, 8) void spmm_slab_merge_kernel(
    const int* __restrict__ rsp, const int2* __restrict__ csr,
    const ushort4* __restrict__ x4 /*e2*/, const ushort4* __restrict__ e0,
    const ushort4* __restrict__ e1, float4* __restrict__ out) {
    __shared__ float acc[RPB * DIM];
    int t = threadIdx.x, b = blockIdx.x;
    int grp = t >> 4, ch = t & 15;
    for (int i = t; i < RPB * DIM; i += 256) acc[i] = 0.f;
    __syncthreads();
    float4* acc4 = (float4*)acc;
    for (int s = 0; s < NSLAB; s++) {
        for (int rbase = 0; rbase < RPB; rbase += 16) {
            int rl = rbase + grp;
            if (rl >= RPB) continue;
            int idx = b * NKEY + s * RPB + rl;
            int st = rsp[idx], en = rsp[idx + 1];
            if (en <= st) continue;
            float4 f = make_float4(0.f, 0.f, 0.f, 0.f);
            int k = st;
            for (; k + 2 <= en; k += 2) {
                int2 e0v = csr[k], e1v = csr[k + 1];
                ushort4 xa = x4[e0v.x * 16 + ch];
                ushort4 xb = x4[e1v.x * 16 + ch];
                float va = __int_as_float(e0v.y), vb = __int_as_float(e1v.y);
                f.x += va * bf2f(xa.x) + vb * bf2f(xb.x);
                f.y += va * bf2f(xa.y) + vb * bf2f(xb.y);
                f.z += va * bf2f(xa.z) + vb * bf2f(xb.z);
                f.w += va * bf2f(xa.w) + vb * bf2f(xb.w);
            }
            if (k < en) {
                int2 e0v = csr[k];
                ushort4 xa = x4[e0v.x * 16 + ch];
                float va = __int_as_float(e0v.y);
                f.x += va * bf2f(xa.x); f.y += va * bf2f(xa.y);
                f.z += va * bf2f(xa.z); f.w += va * bf2f(xa.w);
            }
            float4 a = acc4[rl * 16 + ch];
            a.x += f.x; a.y += f.y; a.z += f.z; a.w += f.w;
            acc4[rl * 16 + ch] = a;
        }
    }
    __syncthreads();
    int rbeg = b * RPB;
    int nr = min(RPB, N_TOTAL - rbeg);
    for (int i = t; i < nr * 16; i += 256) {
        int rl = i >> 4, c = i & 15;
        int o = (rbeg + rl) * 16 + c;
        float4 a = acc4[rl * 16 + c];
        ushort4 p0 = e0[o], p1 = e1[o], p2 = x4[o];
        float4 oo;
        oo.x = (bf2f(p0.x) + bf2f(p1.x) + bf2f(p2.x) + a.x) * 0.25f;
        oo.y = (bf2f(p0.y) + bf2f(p1.y) + bf2f(p2.y) + a.y) * 0.25f;
        oo.z = (bf2f(p0.z) + bf2f(p1.z) + bf2f(p2.z) + a.z) * 0.25f;
        oo.w = (bf2f(p0.w) + bf2f(p1.w) + bf2f(p2.w) + a.w) * 0.25f;
        out[o] = oo;
    }
}

extern "C" void kernel_launch(void* const* d_in, const int* in_sizes, int n_in,
                              void* d_out, int out_size, void* d_ws, size_t ws_size,
                              hipStream_t stream) {
    const float* user_emb = (const float*)d_in[0];
    const float* item_emb = (const float*)d_in[1];
    const int*   adj_row  = (const int*)d_in[2];
    const int*   adj_col  = (const int*)d_in[3];
    const float* adj_vals = (const float*)d_in[4];
    float* out = (float*)d_out;

    ush*   A          = (ush*)d_ws;                 // 19.2 MB (e0)
    ush*   B          = A + NELEM;                  // 19.2 MB (e1)
    ush*   C          = B + NELEM;                  // 19.2 MB (e2)
    uint2* entries    = (uint2*)(C + NELEM);        // 38.4 MB (fine CSR)
    ush*   histmat    = (ush*)(entries + NNZ_C);    // 3.28 MB
    ush*   basemat    = histmat + NBLK * NB;        // 3.28 MB
    ush*   tilesum    = basemat + NBLK * NB;        // 128 KB
    ush*   tilebase   = tilesum + TILES * NB;       // 128 KB
    int*   bucketbase = (int*)(tilebase + TILES * NB);   // 2049 ints
    int*   rsp        = bucketbase + NB + 8;        // 2028*740+1 ints ~ 6 MB

    const int eltBlocks = (NELEM4 + 255) / 256;

    init_kernel<<<eltBlocks, 256, 0, stream>>>(
        (const float4*)user_emb, (const float4*)item_emb, (ushort4*)A);
    p1_hist<<<NBLK, 1024, 0, stream>>>(adj_row, histmat);
    p2a1_tilesum<<<dim3(NB / 256, TILES), 256, 0, stream>>>(histmat, tilesum);
    p2ab_scan<<<1, 1024, 0, stream>>>(tilesum, tilebase, bucketbase, rsp);
    p2a3_expand<<<dim3(NB / 256, TILES), 256, 0, stream>>>(histmat, tilebase,
                                                           basemat);
    p3_scatter<<<NBLK, 1024, 0, stream>>>(adj_row, adj_col, adj_vals,
                                          histmat, basemat, bucketbase, entries);
    p4_sort<<<NB, 512, 0, stream>>>(bucketbase, entries, rsp);

    spmm_slab_kernel<<<NBUCK, 256, 0, stream>>>(rsp, (const int2*)entries,
        (const ushort4*)A, (ushort4*)B);    // e1 = S e0
    spmm_slab_kernel<<<NBUCK, 256, 0, stream>>>(rsp, (const int2*)entries,
        (const ushort4*)B, (ushort4*)C);    // e2 = S e1
    spmm_slab_merge_kernel<<<NBUCK, 256, 0, stream>>>(rsp, (const int2*)entries,
        (const ushort4*)C, (const ushort4*)A, (const ushort4*)B, (float4*)out);
}

// Round 7
// 611.353 us; speedup vs baseline: 1.0364x; 1.0364x over previous
//
#include <hip/hip_runtime.h>

#define N_USERS 100000
#define N_ITEMS 50000
#define N_TOTAL 150000
#define DIM 64
#define NNZ_C 4800000
#define NELEM (N_TOTAL * DIM)        // 9,600,000 elements
#define NELEM4 (NELEM / 4)           // 2,400,000 x4-vectors

#define RPB 74                       // rows per bucket
#define NB 2048                      // buckets (2048*74 >= 150000)
#define NBLK 800                     // scatter blocks
#define CHUNK (NNZ_C / NBLK)         // 6000 nnz per scatter block (exact)
#define TILES 32                     // column-scan tiles over the block dim
#define TB (NBLK / TILES)            // 25 blocks per tile
#define CAP 4096                     // max entries/bucket staged (mean 2344)
#define NBUCK ((N_TOTAL + RPB - 1) / RPB)   // 2028 buckets
#define NSLAB 10                     // column slabs of 16384 cols (2 MB of x)
#define NKEY (NSLAB * RPB)           // 740 sort keys per bucket
#define YSTR 65                      // LDS acc row stride (odd -> bank spread)
#define FXS 33554432.0f              // 2^25 fixed-point scale
#define FXSI (1.0f / 33554432.0f)

typedef unsigned short ush;

__device__ __forceinline__ float bf2f(ush u) {
    return __uint_as_float(((unsigned)u) << 16);
}
__device__ __forceinline__ ush f2bf(float f) {   // round-to-nearest-even
    unsigned u = __float_as_uint(f);
    return (ush)((u + 0x7fffu + ((u >> 16) & 1u)) >> 16);
}

// init: A(bf16) = concat(user,item) = e0
__global__ __launch_bounds__(256) void init_kernel(
    const float4* __restrict__ user, const float4* __restrict__ item,
    ushort4* __restrict__ A16) {
    int i = blockIdx.x * 256 + threadIdx.x;
    if (i >= NELEM4) return;
    const int u4 = N_USERS * DIM / 4;
    float4 v = (i < u4) ? user[i] : item[i - u4];
    ushort4 b;
    b.x = f2bf(v.x); b.y = f2bf(v.y); b.z = f2bf(v.z); b.w = f2bf(v.w);
    A16[i] = b;
}

// P1: per-block bucket histogram in LDS -> histmat[block][bucket] (ushort)
__global__ __launch_bounds__(1024) void p1_hist(
    const int* __restrict__ row, ush* __restrict__ histmat) {
    __shared__ int h[NB];
    int t = threadIdx.x, b = blockIdx.x;
    for (int j = t; j < NB; j += 1024) h[j] = 0;
    __syncthreads();
    int kbeg = b * CHUNK;
    for (int k = kbeg + t; k < kbeg + CHUNK; k += 1024) {
        unsigned r = (unsigned)row[k];
        atomicAdd(&h[r / RPB], 1);
    }
    __syncthreads();
    for (int j = t; j < NB; j += 1024) histmat[b * NB + j] = (ush)h[j];
}

// p2a1: tilesum[tile][j] = sum of TB consecutive blocks' counts
__global__ __launch_bounds__(256) void p2a1_tilesum(
    const ush* __restrict__ histmat, ush* __restrict__ tilesum) {
    int j = blockIdx.x * 256 + threadIdx.x;
    int b0 = blockIdx.y * TB;
    int s = 0;
    #pragma unroll
    for (int i = 0; i < TB; i++) s += histmat[(b0 + i) * NB + j];
    tilesum[blockIdx.y * NB + j] = (ush)s;
}

// p2ab: per-column scan over tile sums -> tilebase; exclusive scan of
// bucket totals -> bucketbase; plus the rsp sentinel.
__global__ __launch_bounds__(1024) void p2ab_scan(
    const ush* __restrict__ tilesum, ush* __restrict__ tilebase,
    int* __restrict__ bucketbase, int* __restrict__ rsp) {
    __shared__ int s[1024];
    int t = threadIdx.x;
    int j0 = 2 * t, j1 = 2 * t + 1;
    int r0 = 0, r1 = 0;
    #pragma unroll
    for (int tl = 0; tl < TILES; tl++) {
        tilebase[tl * NB + j0] = (ush)r0;
        tilebase[tl * NB + j1] = (ush)r1;
        r0 += tilesum[tl * NB + j0];
        r1 += tilesum[tl * NB + j1];
    }
    int pair = r0 + r1;
    s[t] = pair;
    __syncthreads();
    for (int off = 1; off < 1024; off <<= 1) {
        int w = (t >= off) ? s[t - off] : 0;
        __syncthreads();
        s[t] += w;
        __syncthreads();
    }
    int excl = s[t] - pair;
    bucketbase[j0] = excl;
    bucketbase[j1] = excl + r0;
    if (t == 1023) { bucketbase[NB] = s[t]; rsp[NB * NSLAB] = NNZ_C; }
}

// p2a3: expand within each tile -> basemat[b][j]
__global__ __launch_bounds__(256) void p2a3_expand(
    const ush* __restrict__ histmat, const ush* __restrict__ tilebase,
    ush* __restrict__ basemat) {
    int j = blockIdx.x * 256 + threadIdx.x;
    int b0 = blockIdx.y * TB;
    int run = tilebase[blockIdx.y * NB + j];
    #pragma unroll
    for (int i = 0; i < TB; i++) {
        basemat[(b0 + i) * NB + j] = (ush)run;
        run += histmat[(b0 + i) * NB + j];
    }
}

// P3: bucket-sort the chunk in LDS, write runs of consecutive global slots.
// Values are pre-scaled by 2^25 (fixed-point) here.
__global__ __launch_bounds__(1024) void p3_scatter(
    const int* __restrict__ row, const int* __restrict__ col,
    const float* __restrict__ vals, const ush* __restrict__ histmat,
    const ush* __restrict__ basemat, const int* __restrict__ bucketbase,
    uint2* __restrict__ entries) {
    __shared__ int s[1024];
    __shared__ int wp[NB];
    __shared__ int gbase[NB];
    __shared__ uint2 sorted[CHUNK];
    __shared__ ush jarr[CHUNK];
    int t = threadIdx.x, b = blockIdx.x;

    int c0 = histmat[b * NB + 2 * t];
    int c1 = histmat[b * NB + 2 * t + 1];
    int pair = c0 + c1;
    s[t] = pair;
    __syncthreads();
    for (int off = 1; off < 1024; off <<= 1) {
        int w = (t >= off) ? s[t - off] : 0;
        __syncthreads();
        s[t] += w;
        __syncthreads();
    }
    int excl = s[t] - pair;
    wp[2 * t] = excl;
    wp[2 * t + 1] = excl + c0;
    gbase[2 * t]     = bucketbase[2 * t]     + (int)basemat[b * NB + 2 * t]     - excl;
    gbase[2 * t + 1] = bucketbase[2 * t + 1] + (int)basemat[b * NB + 2 * t + 1] - (excl + c0);
    __syncthreads();

    int kbeg = b * CHUNK;
    for (int k = kbeg + t; k < kbeg + CHUNK; k += 1024) {
        unsigned r = (unsigned)row[k];
        unsigned j = r / RPB;
        unsigned rl = r - j * RPB;
        int pos = atomicAdd(&wp[j], 1);
        sorted[pos] = make_uint2((rl << 18) | (unsigned)col[k],
                                 __float_as_uint(vals[k] * FXS));
        jarr[pos] = (ush)j;
    }
    __syncthreads();
    for (int i = t; i < CHUNK; i += 1024)
        entries[gbase[jarr[i]] + i] = sorted[i];
}

// P4: one block per bucket; counting-sort by key = (col-slab, local row).
// Fine entries KEEP the rl tag; rsp emitted at slab granularity (10/bucket).
__global__ __launch_bounds__(512) void p4_sort(
    const int* __restrict__ bucketbase, uint2* __restrict__ entries,
    int* __restrict__ rsp) {
    __shared__ uint2 stage[CAP];       // 32 KB
    __shared__ int cnt[1024];
    __shared__ int s[512];
    __shared__ int wp[1024];
    int t = threadIdx.x, b = blockIdx.x;
    int base = bucketbase[b];
    int n = bucketbase[b + 1] - base;
    if (n > CAP) n = CAP;
    cnt[t] = 0; cnt[t + 512] = 0;
    __syncthreads();
    for (int i = t; i < n; i += 512) {
        uint2 e = entries[base + i];
        stage[i] = e;
        int key = (int)((e.x & 0x3FFFFu) >> 14) * RPB + (int)(e.x >> 18);
        atomicAdd(&cnt[key], 1);
    }
    __syncthreads();
    int c0 = cnt[2 * t], c1 = cnt[2 * t + 1];
    int pair = c0 + c1;
    s[t] = pair;
    __syncthreads();
    for (int off = 1; off < 512; off <<= 1) {
        int w = (t >= off) ? s[t - off] : 0;
        __syncthreads();
        s[t] += w;
        __syncthreads();
    }
    int excl = s[t] - pair;
    wp[2 * t] = excl;
    wp[2 * t + 1] = excl + c0;
    __syncthreads();
    if (t < NSLAB) rsp[b * NSLAB + t] = base + wp[t * RPB];
    __syncthreads();                    // rsp emitted before wp mutates
    for (int i = t; i < n; i += 512) {
        uint2 e = stage[i];
        int key = (int)((e.x & 0x3FFFFu) >> 14) * RPB + (int)(e.x >> 18);
        int pos = atomicAdd(&wp[key], 1);
        entries[base + pos] = e;        // keep rl tag
    }
}

// Slab SpMM v2: block per bucket (2028 ~ 8/CU); slab-major sweep keeps the
// 2 MB x-slab L2-resident (proven: FETCH halved, round 6). Within a slab
// the bucket's entries are ONE contiguous run -> 16-entry batched loop
// (proven MLP engine). Accumulate int32 fixed-point in LDS via native
// ds_add (atomicAdd(int) — float LDS atomics are a CAS loop, rounds 3/4).
// Entries rl-sorted within slab -> register run-coalescing cuts flushes ~3x.
__global__ __launch_bounds__(256, 8) void spmm_slabfx_kernel(
    const int* __restrict__ rsp, const uint2* __restrict__ entries,
    const ushort4* __restrict__ x4, ushort4* __restrict__ y4) {
    __shared__ int acc[RPB * YSTR];    // 19240 B -> 8 blocks/CU
    int t = threadIdx.x, b = blockIdx.x;
    int chunk = t & 15;
    for (int i = t; i < RPB * YSTR; i += 256) acc[i] = 0;
    __syncthreads();
    for (int s = 0; s < NSLAB; s++) {
        int st = rsp[b * NSLAB + s];
        int n_s = rsp[b * NSLAB + s + 1] - st;
        for (int j0 = (t >> 4) * 16; j0 < n_s; j0 += 256) {
            int cnt = min(16, n_s - j0);
            float4 f = make_float4(0.f, 0.f, 0.f, 0.f);
            int crl = -1;
            #pragma unroll 4
            for (int tt = 0; tt < cnt; tt++) {
                uint2 e = entries[st + j0 + tt];    // group-uniform broadcast
                float vv = __uint_as_float(e.y);    // pre-scaled by 2^25
                int cc = (int)(e.x & 0x3FFFFu);
                int rl = (int)(e.x >> 18);
                if (rl != crl) {
                    if (crl >= 0) {
                        int* ap = &acc[crl * YSTR + chunk * 4];
                        atomicAdd(ap + 0, (int)f.x);
                        atomicAdd(ap + 1, (int)f.y);
                        atomicAdd(ap + 2, (int)f.z);
                        atomicAdd(ap + 3, (int)f.w);
                        f = make_float4(0.f, 0.f, 0.f, 0.f);
                    }
                    crl = rl;
                }
                ushort4 xv = x4[cc * 16 + chunk];
                f.x += vv * bf2f(xv.x);
                f.y += vv * bf2f(xv.y);
                f.z += vv * bf2f(xv.z);
                f.w += vv * bf2f(xv.w);
            }
            if (crl >= 0) {
                int* ap = &acc[crl * YSTR + chunk * 4];
                atomicAdd(ap + 0, (int)f.x);
                atomicAdd(ap + 1, (int)f.y);
                atomicAdd(ap + 2, (int)f.z);
                atomicAdd(ap + 3, (int)f.w);
            }
        }
    }
    __syncthreads();
    int rbeg = b * RPB;
    int nr = min(RPB, N_TOTAL - rbeg);
    for (int i = t; i < nr * 16; i += 256) {
        int rl = i >> 4, c = i & 15;
        const int* ap = &acc[rl * YSTR + c * 4];
        ushort4 o;
        o.x = f2bf((float)ap[0] * FXSI);
        o.y = f2bf((float)ap[1] * FXSI);
        o.z = f2bf((float)ap[2] * FXSI);
        o.w = f2bf((float)ap[3] * FXSI);
        y4[(rbeg + rl) * 16 + c] = o;
    }
}

// final layer fused with merge: out = (e0 + e1 + e2 + S*e2) * 0.25
__global__ __launch_bounds__(256, 8) void spmm_slabfx_merge_kernel(
    const int* __restrict__ rsp, const uint2* __restrict__ entries,
    const ushort4* __restrict__ x4 /*e2*/, const ushort4* __restrict__ e0,
    const ushort4* __restrict__ e1, float4* __restrict__ out) {
    __shared__ int acc[RPB * YSTR];
    int t = threadIdx.x, b = blockIdx.x;
    int chunk = t & 15;
    for (int i = t; i < RPB * YSTR; i += 256) acc[i] = 0;
    __syncthreads();
    for (int s = 0; s < NSLAB; s++) {
        int st = rsp[b * NSLAB + s];
        int n_s = rsp[b * NSLAB + s + 1] - st;
        for (int j0 = (t >> 4) * 16; j0 < n_s; j0 += 256) {
            int cnt = min(16, n_s - j0);
            float4 f = make_float4(0.f, 0.f, 0.f, 0.f);
            int crl = -1;
            #pragma unroll 4
            for (int tt = 0; tt < cnt; tt++) {
                uint2 e = entries[st + j0 + tt];
                float vv = __uint_as_float(e.y);
                int cc = (int)(e.x & 0x3FFFFu);
                int rl = (int)(e.x >> 18);
                if (rl != crl) {
                    if (crl >= 0) {
                        int* ap = &acc[crl * YSTR + chunk * 4];
                        atomicAdd(ap + 0, (int)f.x);
                        atomicAdd(ap + 1, (int)f.y);
                        atomicAdd(ap + 2, (int)f.z);
                        atomicAdd(ap + 3, (int)f.w);
                        f = make_float4(0.f, 0.f, 0.f, 0.f);
                    }
                    crl = rl;
                }
                ushort4 xv = x4[cc * 16 + chunk];
                f.x += vv * bf2f(xv.x);
                f.y += vv * bf2f(xv.y);
                f.z += vv * bf2f(xv.z);
                f.w += vv * bf2f(xv.w);
            }
            if (crl >= 0) {
                int* ap = &acc[crl * YSTR + chunk * 4];
                atomicAdd(ap + 0, (int)f.x);
                atomicAdd(ap + 1, (int)f.y);
                atomicAdd(ap + 2, (int)f.z);
                atomicAdd(ap + 3, (int)f.w);
            }
        }
    }
    __syncthreads();
    int rbeg = b * RPB;
    int nr = min(RPB, N_TOTAL - rbeg);
    for (int i = t; i < nr * 16; i += 256) {
        int rl = i >> 4, c = i & 15;
        int o = (rbeg + rl) * 16 + c;
        const int* ap = &acc[rl * YSTR + c * 4];
        ushort4 p0 = e0[o], p1 = e1[o], p2 = x4[o];
        float4 oo;
        oo.x = (bf2f(p0.x) + bf2f(p1.x) + bf2f(p2.x) + (float)ap[0] * FXSI) * 0.25f;
        oo.y = (bf2f(p0.y) + bf2f(p1.y) + bf2f(p2.y) + (float)ap[1] * FXSI) * 0.25f;
        oo.z = (bf2f(p0.z) + bf2f(p1.z) + bf2f(p2.z) + (float)ap[2] * FXSI) * 0.25f;
        oo.w = (bf2f(p0.w) + bf2f(p1.w) + bf2f(p2.w) + (float)ap[3] * FXSI) * 0.25f;
        out[o] = oo;
    }
}

extern "C" void kernel_launch(void* const* d_in, const int* in_sizes, int n_in,
                              void* d_out, int out_size, void* d_ws, size_t ws_size,
                              hipStream_t stream) {
    const float* user_emb = (const float*)d_in[0];
    const float* item_emb = (const float*)d_in[1];
    const int*   adj_row  = (const int*)d_in[2];
    const int*   adj_col  = (const int*)d_in[3];
    const float* adj_vals = (const float*)d_in[4];
    float* out = (float*)d_out;

    ush*   A          = (ush*)d_ws;                 // 19.2 MB (e0)
    ush*   B          = A + NELEM;                  // 19.2 MB (e1)
    ush*   C          = B + NELEM;                  // 19.2 MB (e2)
    uint2* entries    = (uint2*)(C + NELEM);        // 38.4 MB (fine, rl-tagged)
    ush*   histmat    = (ush*)(entries + NNZ_C);    // 3.28 MB
    ush*   basemat    = histmat + NBLK * NB;        // 3.28 MB
    ush*   tilesum    = basemat + NBLK * NB;        // 128 KB
    ush*   tilebase   = tilesum + TILES * NB;       // 128 KB
    int*   bucketbase = (int*)(tilebase + TILES * NB);   // 2049 ints
    int*   rsp        = bucketbase + NB + 8;        // NB*NSLAB+1 ints (~80 KB)

    const int eltBlocks = (NELEM4 + 255) / 256;

    init_kernel<<<eltBlocks, 256, 0, stream>>>(
        (const float4*)user_emb, (const float4*)item_emb, (ushort4*)A);
    p1_hist<<<NBLK, 1024, 0, stream>>>(adj_row, histmat);
    p2a1_tilesum<<<dim3(NB / 256, TILES), 256, 0, stream>>>(histmat, tilesum);
    p2ab_scan<<<1, 1024, 0, stream>>>(tilesum, tilebase, bucketbase, rsp);
    p2a3_expand<<<dim3(NB / 256, TILES), 256, 0, stream>>>(histmat, tilebase,
                                                           basemat);
    p3_scatter<<<NBLK, 1024, 0, stream>>>(adj_row, adj_col, adj_vals,
                                          histmat, basemat, bucketbase, entries);
    p4_sort<<<NB, 512, 0, stream>>>(bucketbase, entries, rsp);

    spmm_slabfx_kernel<<<NBUCK, 256, 0, stream>>>(rsp, entries,
        (const ushort4*)A, (ushort4*)B);    // e1 = S e0
    spmm_slabfx_kernel<<<NBUCK, 256, 0, stream>>>(rsp, entries,
        (const ushort4*)B, (ushort4*)C);    // e2 = S e1
    spmm_slabfx_merge_kernel<<<NBUCK, 256, 0, stream>>>(rsp, entries,
        (const ushort4*)C, (const ushort4*)A, (const ushort4*)B, (float4*)out);
}

// Round 8
// 505.184 us; speedup vs baseline: 1.2543x; 1.2102x over previous
//
#include <hip/hip_runtime.h>

#define N_USERS 100000
#define N_ITEMS 50000
#define N_TOTAL 150000
#define DIM 64
#define NNZ_C 4800000
#define NELEM (N_TOTAL * DIM)        // 9,600,000 elements
#define NELEM4 (NELEM / 4)           // 2,400,000 x4-vectors

#define RPB 74                       // rows per bucket
#define NB 2048                      // buckets (2048*74 >= 150000)
#define NBLK 512                     // scatter blocks
#define CHUNK (NNZ_C / NBLK)         // 9375 nnz per scatter block (exact)
#define TILES 32                     // column-scan tiles over the block dim
#define TB (NBLK / TILES)            // 16 blocks per tile
#define CAP 4096                     // max entries/bucket staged (mean 2344)

typedef unsigned short ush;
typedef unsigned short ushort8 __attribute__((ext_vector_type(8)));

__device__ __forceinline__ float bf2f(ush u) {
    return __uint_as_float(((unsigned)u) << 16);
}
__device__ __forceinline__ ush f2bf(float f) {   // round-to-nearest-even
    unsigned u = __float_as_uint(f);
    return (ush)((u + 0x7fffu + ((u >> 16) & 1u)) >> 16);
}

// init: A(bf16) = concat(user,item) = e0
__global__ __launch_bounds__(256) void init_kernel(
    const float4* __restrict__ user, const float4* __restrict__ item,
    ushort4* __restrict__ A16) {
    int i = blockIdx.x * 256 + threadIdx.x;
    if (i >= NELEM4) return;
    const int u4 = N_USERS * DIM / 4;
    float4 v = (i < u4) ? user[i] : item[i - u4];
    ushort4 b;
    b.x = f2bf(v.x); b.y = f2bf(v.y); b.z = f2bf(v.z); b.w = f2bf(v.w);
    A16[i] = b;
}

// P1: per-block bucket histogram in LDS -> histmat[block][bucket]
__global__ __launch_bounds__(1024) void p1_hist(
    const int* __restrict__ row, int* __restrict__ histmat) {
    __shared__ int h[NB];
    int t = threadIdx.x, b = blockIdx.x;
    for (int j = t; j < NB; j += 1024) h[j] = 0;
    __syncthreads();
    int kbeg = b * CHUNK, kend = kbeg + CHUNK;
    for (int k = kbeg + t; k < kend; k += 1024) {
        unsigned r = (unsigned)row[k];
        atomicAdd(&h[r / RPB], 1);
    }
    __syncthreads();
    for (int j = t; j < NB; j += 1024) histmat[b * NB + j] = h[j];
}

// p2a1: tilesum[tile][j] = sum of 16 consecutive blocks' counts (coalesced)
__global__ __launch_bounds__(256) void p2a1_tilesum(
    const int* __restrict__ histmat, int* __restrict__ tilesum) {
    int j = blockIdx.x * 256 + threadIdx.x;   // 0..NB-1
    int tile = blockIdx.y;                    // 0..TILES-1
    int b0 = tile * TB;
    int s = 0;
    #pragma unroll
    for (int i = 0; i < TB; i++) s += histmat[(b0 + i) * NB + j];
    tilesum[tile * NB + j] = s;
}

// p2a2: per-column scan over the 32 tile sums -> tilebase, bucket totals T
__global__ __launch_bounds__(256) void p2a2_tilescan(
    const int* __restrict__ tilesum, int* __restrict__ tilebase,
    int* __restrict__ T) {
    int j = blockIdx.x * 256 + threadIdx.x;   // 0..NB-1
    int run = 0;
    #pragma unroll
    for (int t = 0; t < TILES; t++) {
        tilebase[t * NB + j] = run;
        run += tilesum[t * NB + j];
    }
    T[j] = run;
}

// p2a3: expand within each tile -> basemat[b][j] = sum_{b'<b} hist (coalesced)
__global__ __launch_bounds__(256) void p2a3_expand(
    const int* __restrict__ histmat, const int* __restrict__ tilebase,
    int* __restrict__ basemat) {
    int j = blockIdx.x * 256 + threadIdx.x;   // 0..NB-1
    int tile = blockIdx.y;                    // 0..TILES-1
    int b0 = tile * TB;
    int run = tilebase[tile * NB + j];
    #pragma unroll
    for (int i = 0; i < TB; i++) {
        basemat[(b0 + i) * NB + j] = run;
        run += histmat[(b0 + i) * NB + j];
    }
}

// P2b: single block exclusive scan of T[2048] -> bucketbase[0..2048]
__global__ __launch_bounds__(1024) void p2b_scan(
    const int* __restrict__ T, int* __restrict__ bucketbase,
    int* __restrict__ rowptr) {
    __shared__ int s[1024];
    int t = threadIdx.x;
    int v0 = T[2 * t], v1 = T[2 * t + 1];
    int pair = v0 + v1;
    s[t] = pair;
    __syncthreads();
    for (int off = 1; off < 1024; off <<= 1) {
        int w = (t >= off) ? s[t - off] : 0;
        __syncthreads();
        s[t] += w;
        __syncthreads();
    }
    int excl = s[t] - pair;
    bucketbase[2 * t] = excl;
    bucketbase[2 * t + 1] = excl + v0;
    if (t == 1023) { bucketbase[NB] = s[t]; rowptr[N_TOTAL] = NNZ_C; }
}

// P3: bucket-sort the chunk in LDS, then write runs of consecutive global
// slots (~4.6 entries per (block,bucket) segment). LDS ~133KB -> 1 block/CU.
__global__ __launch_bounds__(1024) void p3_scatter(
    const int* __restrict__ row, const int* __restrict__ col,
    const float* __restrict__ vals, const int* __restrict__ histmat,
    const int* __restrict__ basemat, const int* __restrict__ bucketbase,
    uint2* __restrict__ entries) {
    __shared__ int s[1024];
    __shared__ int wp[NB];       // running LDS write position per bucket
    __shared__ int gbase[NB];    // global dest = gbase[j] + local pos
    __shared__ uint2 sorted[CHUNK];
    __shared__ int dest[CHUNK];
    int t = threadIdx.x, b = blockIdx.x;

    int c0 = histmat[b * NB + 2 * t];
    int c1 = histmat[b * NB + 2 * t + 1];
    int pair = c0 + c1;
    s[t] = pair;
    __syncthreads();
    for (int off = 1; off < 1024; off <<= 1) {
        int w = (t >= off) ? s[t - off] : 0;
        __syncthreads();
        s[t] += w;
        __syncthreads();
    }
    int excl = s[t] - pair;              // lofs of bucket 2t
    wp[2 * t] = excl;
    wp[2 * t + 1] = excl + c0;
    gbase[2 * t]     = bucketbase[2 * t]     + basemat[b * NB + 2 * t]     - excl;
    gbase[2 * t + 1] = bucketbase[2 * t + 1] + basemat[b * NB + 2 * t + 1] - (excl + c0);
    __syncthreads();

    int kbeg = b * CHUNK, kend = kbeg + CHUNK;
    for (int k = kbeg + t; k < kend; k += 1024) {
        unsigned r = (unsigned)row[k];
        unsigned j = r / RPB;
        unsigned rl = r - j * RPB;
        int pos = atomicAdd(&wp[j], 1);
        sorted[pos] = make_uint2((rl << 18) | (unsigned)col[k],
                                 __float_as_uint(vals[k]));
        dest[pos] = gbase[j] + pos;
    }
    __syncthreads();
    for (int i = t; i < CHUNK; i += 1024)
        entries[dest[i]] = sorted[i];
}

// P4: one block per bucket; stage in LDS, counting-sort by 74 local rows,
// rewrite region in place as fine CSR int2{col,val}; emit rowptr.
__global__ __launch_bounds__(512) void p4_sort(
    const int* __restrict__ bucketbase, uint2* __restrict__ entries,
    int* __restrict__ rowptr) {
    __shared__ uint2 stage[CAP];
    __shared__ int cnt[128], scanb[128], wp[128];
    int t = threadIdx.x, b = blockIdx.x;
    int base = bucketbase[b];
    int n = bucketbase[b + 1] - base;
    if (n > CAP) n = CAP;   // statistically impossible; avoids LDS overrun
    if (t < 128) cnt[t] = 0;
    __syncthreads();
    for (int i = t; i < n; i += 512) {
        uint2 e = entries[base + i];
        stage[i] = e;
        atomicAdd(&cnt[e.x >> 18], 1);
    }
    __syncthreads();
    if (t < 128) scanb[t] = cnt[t];
    __syncthreads();
    for (int off = 1; off < 128; off <<= 1) {
        int w = 0;
        if (t < 128 && t >= off) w = scanb[t - off];
        __syncthreads();
        if (t < 128) scanb[t] += w;
        __syncthreads();
    }
    if (t < RPB) {
        int excl = scanb[t] - cnt[t];
        wp[t] = excl;
        int rg = b * RPB + t;
        if (rg < N_TOTAL) rowptr[rg] = base + excl;
    }
    __syncthreads();
    for (int i = t; i < n; i += 512) {
        uint2 e = stage[i];
        unsigned rl = e.x >> 18;
        int pos = atomicAdd(&wp[rl], 1);
        ((int2*)entries)[base + pos] =
            make_int2((int)(e.x & 0x3FFFFu), (int)e.y);
    }
}

// 8 rows/wave, 8 lanes/row, 16B/lane bf16 gathers, register accumulation.
// vs the 4-row variant: 8 gather-lines in flight per wave (2x line-MLP),
// half the shfl steps. Same per-lane summation order -> identical numerics.
__global__ __launch_bounds__(256) void spmm_csr_kernel(
    const int* __restrict__ rowptr, const int2* __restrict__ csr,
    const ushort8* __restrict__ x8, ushort8* __restrict__ y8) {
    int gid = blockIdx.x * 256 + threadIdx.x;
    int lane = threadIdx.x & 63;
    int group = lane >> 3;           // 8 groups per wave
    int chunk = lane & 7;            // 8 lanes per row
    int r = (gid >> 6) * 8 + group;
    if (r >= N_TOTAL) return;
    int start = rowptr[r], end = rowptr[r + 1];
    float acc[8];
    #pragma unroll
    for (int k = 0; k < 8; k++) acc[k] = 0.f;
    for (int j0 = start; j0 < end; j0 += 8) {
        int j = j0 + chunk;
        int2 pair = make_int2(0, 0);
        if (j < end) pair = csr[j];
        int cnt = min(8, end - j0);
        #pragma unroll 4
        for (int t = 0; t < cnt; t++) {
            int src = group * 8 + t;
            int cc = __shfl(pair.x, src);
            float vv = __int_as_float(__shfl(pair.y, src));
            ushort8 xv = x8[cc * 8 + chunk];
            #pragma unroll
            for (int k = 0; k < 8; k++) acc[k] += vv * bf2f(xv[k]);
        }
    }
    ushort8 yb;
    #pragma unroll
    for (int k = 0; k < 8; k++) yb[k] = f2bf(acc[k]);
    y8[r * 8 + chunk] = yb;
}

// final layer fused with merge: acc = S*e2 (fp32 regs);
// out = (e0 + e1 + e2 + acc) * 0.25
__global__ __launch_bounds__(256) void spmm_merge_kernel(
    const int* __restrict__ rowptr, const int2* __restrict__ csr,
    const ushort8* __restrict__ x8 /*e2*/, const ushort8* __restrict__ e0,
    const ushort8* __restrict__ e1, float4* __restrict__ out) {
    int gid = blockIdx.x * 256 + threadIdx.x;
    int lane = threadIdx.x & 63;
    int group = lane >> 3;
    int chunk = lane & 7;
    int r = (gid >> 6) * 8 + group;
    if (r >= N_TOTAL) return;
    int start = rowptr[r], end = rowptr[r + 1];
    float acc[8];
    #pragma unroll
    for (int k = 0; k < 8; k++) acc[k] = 0.f;
    for (int j0 = start; j0 < end; j0 += 8) {
        int j = j0 + chunk;
        int2 pair = make_int2(0, 0);
        if (j < end) pair = csr[j];
        int cnt = min(8, end - j0);
        #pragma unroll 4
        for (int t = 0; t < cnt; t++) {
            int src = group * 8 + t;
            int cc = __shfl(pair.x, src);
            float vv = __int_as_float(__shfl(pair.y, src));
            ushort8 xv = x8[cc * 8 + chunk];
            #pragma unroll
            for (int k = 0; k < 8; k++) acc[k] += vv * bf2f(xv[k]);
        }
    }
    int o = r * 8 + chunk;
    ushort8 a = e0[o], b = e1[o], c = x8[o];
    float4 o0, o1;
    o0.x = (bf2f(a[0]) + bf2f(b[0]) + bf2f(c[0]) + acc[0]) * 0.25f;
    o0.y = (bf2f(a[1]) + bf2f(b[1]) + bf2f(c[1]) + acc[1]) * 0.25f;
    o0.z = (bf2f(a[2]) + bf2f(b[2]) + bf2f(c[2]) + acc[2]) * 0.25f;
    o0.w = (bf2f(a[3]) + bf2f(b[3]) + bf2f(c[3]) + acc[3]) * 0.25f;
    o1.x = (bf2f(a[4]) + bf2f(b[4]) + bf2f(c[4]) + acc[4]) * 0.25f;
    o1.y = (bf2f(a[5]) + bf2f(b[5]) + bf2f(c[5]) + acc[5]) * 0.25f;
    o1.z = (bf2f(a[6]) + bf2f(b[6]) + bf2f(c[6]) + acc[6]) * 0.25f;
    o1.w = (bf2f(a[7]) + bf2f(b[7]) + bf2f(c[7]) + acc[7]) * 0.25f;
    out[o * 2]     = o0;
    out[o * 2 + 1] = o1;
}

extern "C" void kernel_launch(void* const* d_in, const int* in_sizes, int n_in,
                              void* d_out, int out_size, void* d_ws, size_t ws_size,
                              hipStream_t stream) {
    const float* user_emb = (const float*)d_in[0];
    const float* item_emb = (const float*)d_in[1];
    const int*   adj_row  = (const int*)d_in[2];
    const int*   adj_col  = (const int*)d_in[3];
    const float* adj_vals = (const float*)d_in[4];
    float* out = (float*)d_out;

    ush*   A          = (ush*)d_ws;                 // 19.2 MB (e0)
    ush*   B          = A + NELEM;                  // 19.2 MB (e1)
    ush*   C          = B + NELEM;                  // 19.2 MB (e2)
    uint2* entries    = (uint2*)(C + NELEM);        // 38.4 MB (becomes fine CSR)
    int*   histmat    = (int*)(entries + NNZ_C);    // 512*2048 = 4 MB
    int*   basemat    = histmat + NBLK * NB;        // 4 MB
    int*   tilesum    = basemat + NBLK * NB;        // 32*2048 = 256 KB
    int*   tilebase   = tilesum + TILES * NB;       // 256 KB
    int*   T          = tilebase + TILES * NB;      // 2048
    int*   bucketbase = T + NB;                     // 2049
    int*   rowptr     = bucketbase + NB + 1;        // 150001

    const int eltBlocks  = (NELEM4 + 255) / 256;
    const int spmmBlocks = (N_TOTAL + 31) / 32;     // 8 rows/wave, 4 waves/block

    init_kernel<<<eltBlocks, 256, 0, stream>>>(
        (const float4*)user_emb, (const float4*)item_emb, (ushort4*)A);
    p1_hist<<<NBLK, 1024, 0, stream>>>(adj_row, histmat);
    p2a1_tilesum<<<dim3(NB / 256, TILES), 256, 0, stream>>>(histmat, tilesum);
    p2a2_tilescan<<<NB / 256, 256, 0, stream>>>(tilesum, tilebase, T);
    p2a3_expand<<<dim3(NB / 256, TILES), 256, 0, stream>>>(histmat, tilebase,
                                                           basemat);
    p2b_scan<<<1, 1024, 0, stream>>>(T, bucketbase, rowptr);
    p3_scatter<<<NBLK, 1024, 0, stream>>>(adj_row, adj_col, adj_vals,
                                          histmat, basemat, bucketbase, entries);
    p4_sort<<<NB, 512, 0, stream>>>(bucketbase, entries, rowptr);

    spmm_csr_kernel<<<spmmBlocks, 256, 0, stream>>>(rowptr, (const int2*)entries,
        (const ushort8*)A, (ushort8*)B);    // e1 = S e0
    spmm_csr_kernel<<<spmmBlocks, 256, 0, stream>>>(rowptr, (const int2*)entries,
        (const ushort8*)B, (ushort8*)C);    // e2 = S e1
    spmm_merge_kernel<<<spmmBlocks, 256, 0, stream>>>(rowptr, (const int2*)entries,
        (const ushort8*)C, (const ushort8*)A, (const ushort8*)B, (float4*)out);
}